// Round 1
// baseline (729.719 us; speedup 1.0000x reference)
//
#include <hip/hip_runtime.h>
#include <math.h>

#define NUM_IN   1024
#define HID      32
#define CROWS    4          // rows per chunk
#define NB_MAX   256        // blocks (one per CU)

// Block = 1024 threads = 16 waves.
// Thread (wv, lane): subk = lane>>4 (0..3), og = lane&15 (outputs 4og..4og+3),
// k-slice = [wv*64 + subk*16, +16). Weights register-resident: 64 VGPR/thread.
__global__ __launch_bounds__(1024, 4) void ga_fused(
    const float* __restrict__ x,
    const float* __restrict__ Vw, const float* __restrict__ Vb,
    const float* __restrict__ Uw, const float* __restrict__ Ub,
    const float* __restrict__ ww, const float* __restrict__ wb,
    float* __restrict__ ws, int nBlocks, int nChunk)
{
  __shared__ float4 xbuf[2][CROWS*256];                 // 32 KB: 2 x (4 rows x 1024 f32)
  __shared__ __align__(16) float red[CROWS][16][64];    // 16 KB partial-dot reduce
  __shared__ float act[CROWS][64];                      // 1 KB activations
  __shared__ float lg[CROWS];                           // chunk logits

  const int tid  = threadIdx.x;
  const int b    = blockIdx.x;
  const int wv   = tid >> 6;
  const int lane = tid & 63;
  const int subk = lane >> 4;
  const int og   = lane & 15;
  const int kq   = wv*16 + subk*4;    // float4 index of this thread's k-slice in a row

  // Load weights: wr[op][q] = W[4og+op][kq*4 + 4q .. +3], W = concat(Vw, Uw)
  float4 wr[4][4];
  #pragma unroll
  for (int op = 0; op < 4; ++op) {
    const int o = og*4 + op;
    const float* Wrow = (o < HID) ? (Vw + (size_t)o*NUM_IN) : (Uw + (size_t)(o-HID)*NUM_IN);
    const float4* W4 = reinterpret_cast<const float4*>(Wrow) + kq;
    #pragma unroll
    for (int q = 0; q < 4; ++q) wr[op][q] = W4[q];
  }

  const float4* xg = reinterpret_cast<const float4*>(x);

  float accv = 0.f;          // this thread's element (tid) of the weighted-sum accumulator
  float M = -INFINITY, S = 0.f;
  int cur = 0;

  // prologue: stage first chunk (chunk index == b)
  xbuf[0][tid] = xg[(size_t)b*(CROWS*256) + tid];
  __syncthreads();

  for (int c = b; c < nChunk; c += nBlocks) {
    const int cn = c + nBlocks;
    float4 pre;
    const bool havePre = (cn < nChunk);
    if (havePre) pre = xg[(size_t)cn*(CROWS*256) + tid];   // prefetch next chunk into regs

    // ---- Phase A: partial dots for 4 rows x 4 outputs over 16-k slice ----
    const float4* xb = &xbuf[cur][0];
    #pragma unroll
    for (int r = 0; r < CROWS; ++r) {
      float4 xq[4];
      #pragma unroll
      for (int q = 0; q < 4; ++q) xq[q] = xb[r*256 + kq + q];   // wave-broadcast reads
      float p[4] = {0.f, 0.f, 0.f, 0.f};
      #pragma unroll
      for (int op = 0; op < 4; ++op) {
        #pragma unroll
        for (int q = 0; q < 4; ++q) {
          p[op] += wr[op][q].x * xq[q].x;
          p[op] += wr[op][q].y * xq[q].y;
          p[op] += wr[op][q].z * xq[q].z;
          p[op] += wr[op][q].w * xq[q].w;
        }
      }
      // reduce over subk (lanes l, l^16, l^32, l^48 share og)
      #pragma unroll
      for (int op = 0; op < 4; ++op) {
        p[op] += __shfl_xor(p[op], 16);
        p[op] += __shfl_xor(p[op], 32);
      }
      if (subk == 0) {
        float4 pv = make_float4(p[0], p[1], p[2], p[3]);
        *reinterpret_cast<float4*>(&red[r][wv][og*4]) = pv;
      }
    }
    __syncthreads();

    // ---- reduce across the 16 waves + activations ----
    if (tid < CROWS*64) {
      const int rr = tid >> 6, oo = tid & 63;
      float s = 0.f;
      #pragma unroll
      for (int k = 0; k < 16; ++k) s += red[rr][k][oo];
      float a;
      if (oo < HID) a = tanhf(s + Vb[oo]);
      else          a = 1.f / (1.f + __expf(-(s + Ub[oo - HID])));
      act[rr][oo] = a;
    }
    __syncthreads();

    // ---- logits: sum_h tanh*sigmoid*ww[h] ----
    if (tid < CROWS*32) {
      const int rr = tid >> 5, h = tid & 31;
      float g = act[rr][h] * act[rr][h + HID] * ww[h];
      g += __shfl_xor(g, 1);
      g += __shfl_xor(g, 2);
      g += __shfl_xor(g, 4);
      g += __shfl_xor(g, 8);
      g += __shfl_xor(g, 16);
      if (h == 0) lg[rr] = g + wb[0];
    }
    __syncthreads();

    // ---- Phase B: online softmax update (all threads, redundant scalars) ----
    const float* xs = reinterpret_cast<const float*>(&xbuf[cur][0]);
    float l[CROWS];
    #pragma unroll
    for (int r = 0; r < CROWS; ++r) l[r] = lg[r];
    float mc = l[0];
    #pragma unroll
    for (int r = 1; r < CROWS; ++r) mc = fmaxf(mc, l[r]);
    const float newM  = fmaxf(M, mc);
    const float scale = __expf(M - newM);     // first chunk: exp(-inf) = 0
    float ps = 0.f, add = 0.f;
    #pragma unroll
    for (int r = 0; r < CROWS; ++r) {
      const float p = __expf(l[r] - newM);
      ps  += p;
      add += p * xs[r*NUM_IN + tid];
    }
    accv = accv*scale + add;
    S    = S*scale + ps;
    M    = newM;

    // ---- stage prefetched chunk into the other buffer ----
    if (havePre) xbuf[cur ^ 1][tid] = pre;
    __syncthreads();
    cur ^= 1;
  }

  // per-block partial: acc[1024], M, S
  ws[(size_t)b*NUM_IN + tid] = accv;
  if (tid == 0) {
    ws[(size_t)nBlocks*NUM_IN + b]            = M;
    ws[(size_t)nBlocks*NUM_IN + nBlocks + b]  = S;
  }
}

__global__ void ga_combine(const float* __restrict__ ws, float* __restrict__ out, int nBlocks)
{
  const int e = blockIdx.x * blockDim.x + threadIdx.x;   // 0..1023
  const float* wsM = ws + (size_t)nBlocks*NUM_IN;
  const float* wsS = wsM + nBlocks;
  float M = -INFINITY;
  for (int b = 0; b < nBlocks; ++b) M = fmaxf(M, wsM[b]);
  float S = 0.f, m = 0.f;
  for (int b = 0; b < nBlocks; ++b) {
    const float wgt = __expf(wsM[b] - M);
    S += wgt * wsS[b];
    m  = fmaf(wgt, ws[(size_t)b*NUM_IN + e], m);
  }
  out[e] = m / S;
}

extern "C" void kernel_launch(void* const* d_in, const int* in_sizes, int n_in,
                              void* d_out, int out_size, void* d_ws, size_t ws_size,
                              hipStream_t stream)
{
  const float* x  = (const float*)d_in[0];
  const float* Vw = (const float*)d_in[1];
  const float* Vb = (const float*)d_in[2];
  const float* Uw = (const float*)d_in[3];
  const float* Ub = (const float*)d_in[4];
  const float* ww = (const float*)d_in[5];
  const float* wb = (const float*)d_in[6];
  float* out = (float*)d_out;
  float* ws  = (float*)d_ws;

  const int Nrows  = in_sizes[0] / NUM_IN;   // 200000
  const int nChunk = Nrows / CROWS;          // 50000 (exact)

  int nb = NB_MAX;
  size_t need = ((size_t)nb*NUM_IN + 2*(size_t)nb) * sizeof(float);
  while (nb > 1 && need > ws_size) { nb >>= 1; need = ((size_t)nb*NUM_IN + 2*(size_t)nb) * sizeof(float); }

  ga_fused<<<nb, 1024, 0, stream>>>(x, Vw, Vb, Uw, Ub, ww, wb, ws, nb, nChunk);
  ga_combine<<<8, 128, 0, stream>>>(ws, out, nb);
}